// Round 6
// baseline (315.258 us; speedup 1.0000x reference)
//
#include <hip/hip_runtime.h>
#include <hip/hip_bf16.h>
#include <stdint.h>

constexpr int N     = 100000;
constexpr int E     = 1600000;
constexpr int ETOT  = E + N;
constexpr int F     = 256;
constexpr int H     = 8;
constexpr int C     = 16;
constexpr int HC    = H * C;      // 128
constexpr int NCLS  = 16;
constexpr float NEG_SLOPE = 0.2f;

constexpr int BSHIFT = 8;                       // 256 dsts per bucket
constexpr int NBUCK  = (N + 255) >> BSHIFT;     // 391
constexpr int BCAP   = 8192;
constexpr int TILE   = 16384;
constexpr int NTILE  = (ETOT + TILE - 1) / TILE;

constexpr int RECW   = 72;                      // record words: 64 (h1 bf16x128) + 8 (as1 f32)

typedef __attribute__((ext_vector_type(8))) short short8;
typedef __attribute__((ext_vector_type(4))) float f32x4;
typedef __attribute__((ext_vector_type(4))) unsigned int u32x4;

__device__ inline unsigned short f2bf(float f) {
    union { float f; unsigned int u; } v{f};
    unsigned int r = v.u + 0x7FFF + ((v.u >> 16) & 1);   // RNE
    return (unsigned short)(r >> 16);
}
__device__ inline float bf2f(unsigned short s) {
    union { unsigned int u; float f; } v{(unsigned int)s << 16};
    return v.f;
}

// ---------------- CSR build: LDS-staged two-level counting sort ----------------

__global__ __launch_bounds__(256) void k_bhist(const int* __restrict__ ei,
                                               int* __restrict__ bcnt) {
    __shared__ int h[NBUCK];
    for (int i = threadIdx.x; i < NBUCK; i += 256) h[i] = 0;
    __syncthreads();
    int t0 = blockIdx.x * TILE;
    int t1 = (t0 + TILE < ETOT) ? t0 + TILE : ETOT;
    for (int e = t0 + threadIdx.x; e < t1; e += 256) {
        int d = (e < E) ? ei[E + e] : (e - E);
        atomicAdd(&h[d >> BSHIFT], 1);
    }
    __syncthreads();
    for (int i = threadIdx.x; i < NBUCK; i += 256) {
        int c = h[i];
        if (c) atomicAdd(&bcnt[i], c);
    }
}

__global__ void k_bscan(const int* __restrict__ bcnt, int* __restrict__ boff,
                        int* __restrict__ bcur, int* __restrict__ off) {
    __shared__ int s[512];
    int tid = threadIdx.x;
    int v = (tid < NBUCK) ? bcnt[tid] : 0;
    s[tid] = v; __syncthreads();
    for (int ofs = 1; ofs < 512; ofs <<= 1) {
        int t = (tid >= ofs) ? s[tid - ofs] : 0;
        __syncthreads();
        s[tid] += t;
        __syncthreads();
    }
    if (tid < NBUCK) { int ex = s[tid] - v; boff[tid] = ex; bcur[tid] = ex; }
    if (tid == 0) off[N] = ETOT;
}

__global__ __launch_bounds__(256) void k_part(const int* __restrict__ ei,
                                              int* __restrict__ bcur,
                                              uint2* __restrict__ pairs) {
    __shared__ int h[NBUCK];
    __shared__ int base[NBUCK];
    int t0 = blockIdx.x * TILE;
    int t1 = (t0 + TILE < ETOT) ? t0 + TILE : ETOT;
    for (int i = threadIdx.x; i < NBUCK; i += 256) h[i] = 0;
    __syncthreads();
    for (int e = t0 + threadIdx.x; e < t1; e += 256) {
        int d = (e < E) ? ei[E + e] : (e - E);
        atomicAdd(&h[d >> BSHIFT], 1);
    }
    __syncthreads();
    for (int i = threadIdx.x; i < NBUCK; i += 256) {
        int c = h[i];
        base[i] = c ? atomicAdd(&bcur[i], c) : 0;
    }
    __syncthreads();
    for (int i = threadIdx.x; i < NBUCK; i += 256) h[i] = 0;
    __syncthreads();
    for (int e = t0 + threadIdx.x; e < t1; e += 256) {
        int s, d;
        if (e < E) { s = ei[e]; d = ei[E + e]; } else { s = e - E; d = s; }
        int b = d >> BSHIFT;
        int r = atomicAdd(&h[b], 1);
        pairs[base[b] + r] = make_uint2((unsigned)s, (unsigned)d);
    }
}

__global__ __launch_bounds__(256) void k_bsort(const uint2* __restrict__ pairs,
                                               const int* __restrict__ bcnt,
                                               const int* __restrict__ boff,
                                               int* __restrict__ csr,
                                               int* __restrict__ off) {
    __shared__ int srcs[BCAP];
    __shared__ int csrs[BCAP];
    __shared__ unsigned char dl[BCAP];
    __shared__ int hist[256];
    __shared__ int sc[256];
    int b = blockIdx.x;
    int nb = bcnt[b]; if (nb > BCAP) nb = BCAP;
    int base = boff[b];
    int dbase = b << BSHIFT;
    int ndst = (N - dbase < 256) ? (N - dbase) : 256;
    int tid = threadIdx.x;

    for (int i = tid; i < nb; i += 256) {
        uint2 p = pairs[base + i];
        srcs[i] = (int)p.x;
        dl[i] = (unsigned char)(p.y & 255);
    }
    hist[tid] = 0;
    __syncthreads();
    for (int i = tid; i < nb; i += 256) atomicAdd(&hist[dl[i]], 1);
    __syncthreads();
    int v = hist[tid];
    sc[tid] = v;
    __syncthreads();
    for (int ofs = 1; ofs < 256; ofs <<= 1) {
        int t = (tid >= ofs) ? sc[tid - ofs] : 0;
        __syncthreads();
        sc[tid] += t;
        __syncthreads();
    }
    int lo = sc[tid] - v;
    if (tid < ndst) off[dbase + tid] = base + lo;
    hist[tid] = lo;
    __syncthreads();
    for (int i = tid; i < nb; i += 256) {
        int r = atomicAdd(&hist[dl[i]], 1);
        csrs[r] = srcs[i];
    }
    __syncthreads();
    for (int i = tid; i < nb; i += 256) csr[base + i] = csrs[i];
}

// ---------------- W1 f32 -> bf16 ----------------

__global__ void k_w1cast(const float* __restrict__ W1, unsigned short* __restrict__ w1b) {
    int i = blockIdx.x * 256 + threadIdx.x;
    if (i < HC * F) w1b[i] = f2bf(W1[i]);
}

// ---------------- gemm1: record.h1 = bf16(x) @ bf16(W1)^T via MFMA ----------------
// h1r record per node: 72 u32 words = [128 bf16 h1 | 8 f32 as1]

__global__ __launch_bounds__(256) void k_gemm1(const float* __restrict__ x,
                                               const unsigned short* __restrict__ w1b,
                                               unsigned short* __restrict__ h1r16) {
    __shared__ unsigned short Ws[HC * F];  // 64KB, XOR-swizzled 16B chunks
    for (int i = threadIdx.x; i < 4096; i += 256) {
        int row = i >> 5;
        int c16 = i & 31;
        u32x4 v = ((const u32x4*)w1b)[i];
        int byte = row * 512 + ((c16 * 16) ^ ((row & 7) << 4));
        *((u32x4*)((char*)Ws + byte)) = v;
    }
    __syncthreads();

    int wid = threadIdx.x >> 6, lane = threadIdx.x & 63;
    int r16 = lane & 15, g = lane >> 4;
    int m = blockIdx.x * 64 + wid * 16 + r16;
    int mc = (m < N) ? m : (N - 1);
    const float* xr = x + (size_t)mc * F;

    f32x4 acc[8];
#pragma unroll
    for (int nf = 0; nf < 8; ++nf) acc[nf] = (f32x4){0.f, 0.f, 0.f, 0.f};

#pragma unroll
    for (int kk = 0; kk < 8; ++kk) {
        f32x4 a0 = *((const f32x4*)(xr + kk * 32 + g * 8));
        f32x4 a1 = *((const f32x4*)(xr + kk * 32 + g * 8 + 4));
        short8 af;
#pragma unroll
        for (int j = 0; j < 4; ++j) {
            af[j]     = (short)f2bf(a0[j]);
            af[4 + j] = (short)f2bf(a1[j]);
        }
        int kbyte = kk * 64 + g * 16;
#pragma unroll
        for (int nf = 0; nf < 8; ++nf) {
            int row = nf * 16 + r16;
            int byte = row * 512 + (kbyte ^ ((row & 7) << 4));
            short8 bf = *((const short8*)((const char*)Ws + byte));
            acc[nf] = __builtin_amdgcn_mfma_f32_16x16x32_bf16(af, bf, acc[nf], 0, 0, 0);
        }
    }

    int orow = blockIdx.x * 64 + wid * 16 + g * 4;
#pragma unroll
    for (int j = 0; j < 4; ++j) {
        int rr = orow + j;
        if (rr >= N) continue;
        unsigned short* dst = h1r16 + (size_t)rr * (RECW * 2) + r16;
#pragma unroll
        for (int nf = 0; nf < 8; ++nf) dst[nf * 16] = f2bf(acc[nf][j]);
    }
}

// ---------------- attention scores layer 1 (into record + ad1 array) ----------------

__global__ void k_att1(char* __restrict__ h1r,
                       const float* __restrict__ aw_s, const float* __restrict__ aw_d,
                       float* __restrict__ ad1) {
    int idx = blockIdx.x * 256 + threadIdx.x;  // n*8 + h
    if (idx >= N * H) return;
    int n = idx >> 3, h = idx & 7;
    char* rec = h1r + (size_t)n * (RECW * 4);
    const u32x4* hp = (const u32x4*)(rec + h * 32);
    u32x4 v0 = hp[0], v1 = hp[1];
    float s = 0.f, d = 0.f;
#pragma unroll
    for (int q = 0; q < 4; ++q) {
        unsigned int u = v0[q];
        float e0 = bf2f((unsigned short)(u & 0xffff));
        float e1 = bf2f((unsigned short)(u >> 16));
        s += e0 * aw_s[h * 16 + 2 * q] + e1 * aw_s[h * 16 + 2 * q + 1];
        d += e0 * aw_d[h * 16 + 2 * q] + e1 * aw_d[h * 16 + 2 * q + 1];
    }
#pragma unroll
    for (int q = 0; q < 4; ++q) {
        unsigned int u = v1[q];
        float e0 = bf2f((unsigned short)(u & 0xffff));
        float e1 = bf2f((unsigned short)(u >> 16));
        s += e0 * aw_s[h * 16 + 8 + 2 * q] + e1 * aw_s[h * 16 + 8 + 2 * q + 1];
        d += e0 * aw_d[h * 16 + 8 + 2 * q] + e1 * aw_d[h * 16 + 8 + 2 * q + 1];
    }
    ((float*)(rec + 256))[h] = s;
    ad1[idx] = d;
}

// ---------------- layer 1 aggregate: 32-bit saddr indexing, unrolled x4 --------

__global__ __launch_bounds__(256) void k_agg1(const int* __restrict__ off,
                                              const int* __restrict__ csr,
                                              const unsigned int* __restrict__ h1w,
                                              const float* __restrict__ ad1,
                                              const float* __restrict__ b1,
                                              unsigned short* __restrict__ out1b) {
    int w = threadIdx.x >> 6, l = threadIdx.x & 63;
    int n = blockIdx.x * 4 + w;
    if (n >= N) return;
    int hh = l >> 3;
    unsigned int wh = (unsigned int)l;          // word offset of h1 pair
    unsigned int wa = 64u + (unsigned int)hh;   // word offset of as1
    int e0 = off[n], e1 = off[n + 1];
    float adst = ad1[n * H + hh];
    float den = 0.f, acc0 = 0.f, acc1 = 0.f;
    int e = e0;
    for (; e + 4 <= e1; e += 4) {
        unsigned int r0 = (unsigned int)csr[e]     * (unsigned int)RECW;
        unsigned int r1 = (unsigned int)csr[e + 1] * (unsigned int)RECW;
        unsigned int r2 = (unsigned int)csr[e + 2] * (unsigned int)RECW;
        unsigned int r3 = (unsigned int)csr[e + 3] * (unsigned int)RECW;
        float x0 = __uint_as_float(h1w[r0 + wa]);
        float x1 = __uint_as_float(h1w[r1 + wa]);
        float x2 = __uint_as_float(h1w[r2 + wa]);
        float x3 = __uint_as_float(h1w[r3 + wa]);
        unsigned int d0 = h1w[r0 + wh];
        unsigned int d1 = h1w[r1 + wh];
        unsigned int d2 = h1w[r2 + wh];
        unsigned int d3 = h1w[r3 + wh];
        float a0 = x0 + adst; a0 = (a0 > 0.f) ? a0 : NEG_SLOPE * a0;
        float a1 = x1 + adst; a1 = (a1 > 0.f) ? a1 : NEG_SLOPE * a1;
        float a2 = x2 + adst; a2 = (a2 > 0.f) ? a2 : NEG_SLOPE * a2;
        float a3 = x3 + adst; a3 = (a3 > 0.f) ? a3 : NEG_SLOPE * a3;
        float w0 = __expf(a0), w1 = __expf(a1), w2 = __expf(a2), w3 = __expf(a3);
        den += (w0 + w1) + (w2 + w3);
        acc0 += w0 * bf2f((unsigned short)(d0 & 0xffff))
              + w1 * bf2f((unsigned short)(d1 & 0xffff))
              + w2 * bf2f((unsigned short)(d2 & 0xffff))
              + w3 * bf2f((unsigned short)(d3 & 0xffff));
        acc1 += w0 * bf2f((unsigned short)(d0 >> 16))
              + w1 * bf2f((unsigned short)(d1 >> 16))
              + w2 * bf2f((unsigned short)(d2 >> 16))
              + w3 * bf2f((unsigned short)(d3 >> 16));
    }
    for (; e < e1; ++e) {
        unsigned int r = (unsigned int)csr[e] * (unsigned int)RECW;
        float xv = __uint_as_float(h1w[r + wa]);
        float al = xv + adst;
        al = (al > 0.f) ? al : NEG_SLOPE * al;
        float wt = __expf(al);
        den += wt;
        unsigned int d = h1w[r + wh];
        acc0 += wt * bf2f((unsigned short)(d & 0xffff));
        acc1 += wt * bf2f((unsigned short)(d >> 16));
    }
    float inv = 1.f / (den + 1e-16f);
    float v0 = acc0 * inv + b1[2 * l];
    float v1 = acc1 * inv + b1[2 * l + 1];
    v0 = (v0 > 0.f) ? v0 : (__expf(v0) - 1.f);   // ELU
    v1 = (v1 > 0.f) ? v1 : (__expf(v1) - 1.f);
    unsigned int packed = ((unsigned int)f2bf(v1) << 16) | f2bf(v0);
    *((unsigned int*)(out1b + (size_t)n * HC + 2 * l)) = packed;
}

// ---------------- layer 2 GEMM (bf16 in) fused with att scores, bf16 h2 out ----

__global__ __launch_bounds__(256) void k_gemm2(const unsigned short* __restrict__ out1b,
                                               const float* __restrict__ W2,
                                               const float* __restrict__ aw_s2,
                                               const float* __restrict__ aw_d2,
                                               unsigned short* __restrict__ h2b,
                                               float* __restrict__ as2,
                                               float* __restrict__ ad2) {
    __shared__ float Ws[HC * NCLS];  // Ws[k*16+j] = W2[j*128+k]
    for (int i = threadIdx.x; i < HC * NCLS; i += 256) {
        int j = i / HC, k = i % HC;
        Ws[k * NCLS + j] = W2[i];
    }
    __syncthreads();
    int gpos = threadIdx.x >> 4, j = threadIdx.x & 15;
    int n = blockIdx.x * 16 + gpos;
    if (n >= N) return;
    const u32x4* xr = (const u32x4*)(out1b + (size_t)n * HC);
    float acc = 0.f;
#pragma unroll
    for (int q = 0; q < 16; ++q) {
        u32x4 v = xr[q];
#pragma unroll
        for (int t = 0; t < 4; ++t) {
            unsigned int u = v[t];
            float e0 = bf2f((unsigned short)(u & 0xffff));
            float e1 = bf2f((unsigned short)(u >> 16));
            acc += e0 * Ws[(q * 8 + 2 * t) * 16 + j] + e1 * Ws[(q * 8 + 2 * t + 1) * 16 + j];
        }
    }
    h2b[n * NCLS + j] = f2bf(acc);
    float s = acc * aw_s2[j], d = acc * aw_d2[j];
#pragma unroll
    for (int msk = 8; msk >= 1; msk >>= 1) {
        s += __shfl_xor(s, msk, 64);
        d += __shfl_xor(d, msk, 64);
    }
    if (j == 0) { as2[n] = s; ad2[n] = d; }
}

// ---------------- layer 2 aggregate: 16 channels x 4 edge-slots per wave ------

__global__ __launch_bounds__(256) void k_agg2(const int* __restrict__ off,
                                              const int* __restrict__ csr,
                                              const float* __restrict__ as2,
                                              const float* __restrict__ ad2,
                                              const unsigned short* __restrict__ h2b,
                                              const float* __restrict__ b2,
                                              float* __restrict__ outp) {
    int wv = threadIdx.x >> 6, l = threadIdx.x & 63;
    int n = blockIdx.x * 4 + wv;
    if (n >= N) return;
    int c = l & 15, g = l >> 4;      // channel, edge-slot
    int e0 = off[n], e1 = off[n + 1];
    float adst = ad2[n];
    float den = 0.f, acc = 0.f;
    for (int eb = e0; eb < e1; eb += 4) {
        int ei = eb + g;
        bool ok = ei < e1;
        int s = csr[ok ? ei : e0];
        float al = as2[s] + adst;
        al = (al > 0.f) ? al : NEG_SLOPE * al;
        float wt = ok ? __expf(al) : 0.f;
        den += wt;
        acc += wt * bf2f(h2b[(unsigned int)s * 16u + (unsigned int)c]);
    }
    // cross-slot reduction (4 slots)
    acc += __shfl_xor(acc, 16, 64); acc += __shfl_xor(acc, 32, 64);
    den += __shfl_xor(den, 16, 64); den += __shfl_xor(den, 32, 64);
    float v = acc / (den + 1e-16f) + b2[c];
    // log_softmax across 16 channels (within 16-lane group)
    float mx = v;
#pragma unroll
    for (int msk = 8; msk >= 1; msk >>= 1) mx = fmaxf(mx, __shfl_xor(mx, msk, 64));
    float ex = __expf(v - mx), se = ex;
#pragma unroll
    for (int msk = 8; msk >= 1; msk >>= 1) se += __shfl_xor(se, msk, 64);
    if (l < 16) outp[n * NCLS + c] = v - mx - __logf(se);
}

// ---------------- launch ----------------

extern "C" void kernel_launch(void* const* d_in, const int* in_sizes, int n_in,
                              void* d_out, int out_size, void* d_ws, size_t ws_size,
                              hipStream_t stream) {
    const float* x        = (const float*)d_in[0];
    const int*   ei       = (const int*)d_in[1];
    const float* W1       = (const float*)d_in[2];
    const float* att_src1 = (const float*)d_in[3];
    const float* att_dst1 = (const float*)d_in[4];
    const float* b1       = (const float*)d_in[5];
    const float* W2       = (const float*)d_in[6];
    const float* att_src2 = (const float*)d_in[7];
    const float* att_dst2 = (const float*)d_in[8];
    const float* b2       = (const float*)d_in[9];
    float* outp = (float*)d_out;

    char* p = (char*)d_ws;
    char* h1r = p;                             p += (size_t)N * RECW * 4;   // 28.8MB records
    unsigned short* out1b = (unsigned short*)p; p += (size_t)N * HC * 2;    // 25.6MB
    unsigned short* h2b   = (unsigned short*)p; p += (size_t)N * NCLS * 2;  // 3.2MB
    float* ad1  = (float*)p; p += (size_t)N * H * 4;
    float* as2  = (float*)p; p += (size_t)N * 4;
    float* ad2  = (float*)p; p += (size_t)N * 4;
    unsigned short* w1b = (unsigned short*)p; p += (size_t)HC * F * 2;
    uint2* pairs = (uint2*)p; p += (size_t)ETOT * 8;                        // 13.6MB
    int* csr    = (int*)p;   p += (size_t)ETOT * 4;
    int* off    = (int*)p;   p += (size_t)(N + 1) * 4;
    int* bcnt   = (int*)p;   p += (size_t)NBUCK * 4;
    int* boff   = (int*)p;   p += (size_t)NBUCK * 4;
    int* bcur   = (int*)p;   p += (size_t)NBUCK * 4;

    hipMemsetAsync(bcnt, 0, (size_t)NBUCK * 4, stream);

    k_bhist<<<NTILE, 256, 0, stream>>>(ei, bcnt);
    k_bscan<<<1, 512, 0, stream>>>(bcnt, boff, bcur, off);
    k_part<<<NTILE, 256, 0, stream>>>(ei, bcur, pairs);
    k_bsort<<<NBUCK, 256, 0, stream>>>(pairs, bcnt, boff, csr, off);

    k_w1cast<<<(HC * F + 255) / 256, 256, 0, stream>>>(W1, w1b);
    k_gemm1<<<(N + 63) / 64, 256, 0, stream>>>(x, w1b, (unsigned short*)h1r);
    k_att1<<<(N * H + 255) / 256, 256, 0, stream>>>(h1r, att_src1, att_dst1, ad1);
    k_agg1<<<(N + 3) / 4, 256, 0, stream>>>(off, csr, (const unsigned int*)h1r, ad1, b1, out1b);

    k_gemm2<<<(N + 15) / 16, 256, 0, stream>>>(out1b, W2, att_src2, att_dst2, h2b, as2, ad2);
    k_agg2<<<(N + 3) / 4, 256, 0, stream>>>(off, csr, as2, ad2, h2b, b2, outp);
}

// Round 7
// 271.531 us; speedup vs baseline: 1.1610x; 1.1610x over previous
//
#include <hip/hip_runtime.h>
#include <hip/hip_bf16.h>
#include <stdint.h>

constexpr int N     = 100000;
constexpr int E     = 1600000;
constexpr int ETOT  = E + N;
constexpr int F     = 256;
constexpr int H     = 8;
constexpr int C     = 16;
constexpr int HC    = H * C;      // 128
constexpr int NCLS  = 16;
constexpr float NEG_SLOPE = 0.2f;

constexpr int BSHIFT = 8;                       // 256 dsts per bucket
constexpr int NBUCK  = (N + 255) >> BSHIFT;     // 391
constexpr int BCAP   = 8192;
constexpr int TILE   = 16384;
constexpr int NTILE  = (ETOT + TILE - 1) / TILE;

constexpr int RECW   = 72;                      // record words: 64 (h1 bf16x128) + 8 (as1 f32)

typedef __attribute__((ext_vector_type(8))) short short8;
typedef __attribute__((ext_vector_type(4))) float f32x4;
typedef __attribute__((ext_vector_type(4))) unsigned int u32x4;

__device__ inline unsigned short f2bf(float f) {
    union { float f; unsigned int u; } v{f};
    unsigned int r = v.u + 0x7FFF + ((v.u >> 16) & 1);   // RNE
    return (unsigned short)(r >> 16);
}
__device__ inline float bf2f(unsigned short s) {
    union { unsigned int u; float f; } v{(unsigned int)s << 16};
    return v.f;
}

// ---------------- CSR build: LDS-staged two-level counting sort ----------------

__global__ __launch_bounds__(256) void k_bhist(const int* __restrict__ ei,
                                               int* __restrict__ bcnt) {
    __shared__ int h[NBUCK];
    for (int i = threadIdx.x; i < NBUCK; i += 256) h[i] = 0;
    __syncthreads();
    int t0 = blockIdx.x * TILE;
    int t1 = (t0 + TILE < ETOT) ? t0 + TILE : ETOT;
    for (int e = t0 + threadIdx.x; e < t1; e += 256) {
        int d = (e < E) ? ei[E + e] : (e - E);
        atomicAdd(&h[d >> BSHIFT], 1);
    }
    __syncthreads();
    for (int i = threadIdx.x; i < NBUCK; i += 256) {
        int c = h[i];
        if (c) atomicAdd(&bcnt[i], c);
    }
}

__global__ void k_bscan(const int* __restrict__ bcnt, int* __restrict__ boff,
                        int* __restrict__ bcur, int* __restrict__ off) {
    __shared__ int s[512];
    int tid = threadIdx.x;
    int v = (tid < NBUCK) ? bcnt[tid] : 0;
    s[tid] = v; __syncthreads();
    for (int ofs = 1; ofs < 512; ofs <<= 1) {
        int t = (tid >= ofs) ? s[tid - ofs] : 0;
        __syncthreads();
        s[tid] += t;
        __syncthreads();
    }
    if (tid < NBUCK) { int ex = s[tid] - v; boff[tid] = ex; bcur[tid] = ex; }
    if (tid == 0) off[N] = ETOT;
}

__global__ __launch_bounds__(256) void k_part(const int* __restrict__ ei,
                                              int* __restrict__ bcur,
                                              uint2* __restrict__ pairs) {
    __shared__ int h[NBUCK];
    __shared__ int base[NBUCK];
    int t0 = blockIdx.x * TILE;
    int t1 = (t0 + TILE < ETOT) ? t0 + TILE : ETOT;
    for (int i = threadIdx.x; i < NBUCK; i += 256) h[i] = 0;
    __syncthreads();
    for (int e = t0 + threadIdx.x; e < t1; e += 256) {
        int d = (e < E) ? ei[E + e] : (e - E);
        atomicAdd(&h[d >> BSHIFT], 1);
    }
    __syncthreads();
    for (int i = threadIdx.x; i < NBUCK; i += 256) {
        int c = h[i];
        base[i] = c ? atomicAdd(&bcur[i], c) : 0;
    }
    __syncthreads();
    for (int i = threadIdx.x; i < NBUCK; i += 256) h[i] = 0;
    __syncthreads();
    for (int e = t0 + threadIdx.x; e < t1; e += 256) {
        int s, d;
        if (e < E) { s = ei[e]; d = ei[E + e]; } else { s = e - E; d = s; }
        int b = d >> BSHIFT;
        int r = atomicAdd(&h[b], 1);
        pairs[base[b] + r] = make_uint2((unsigned)s, (unsigned)d);
    }
}

__global__ __launch_bounds__(256) void k_bsort(const uint2* __restrict__ pairs,
                                               const int* __restrict__ bcnt,
                                               const int* __restrict__ boff,
                                               int* __restrict__ csr,
                                               int* __restrict__ off) {
    __shared__ int srcs[BCAP];
    __shared__ int csrs[BCAP];
    __shared__ unsigned char dl[BCAP];
    __shared__ int hist[256];
    __shared__ int sc[256];
    int b = blockIdx.x;
    int nb = bcnt[b]; if (nb > BCAP) nb = BCAP;
    int base = boff[b];
    int dbase = b << BSHIFT;
    int ndst = (N - dbase < 256) ? (N - dbase) : 256;
    int tid = threadIdx.x;

    for (int i = tid; i < nb; i += 256) {
        uint2 p = pairs[base + i];
        srcs[i] = (int)p.x;
        dl[i] = (unsigned char)(p.y & 255);
    }
    hist[tid] = 0;
    __syncthreads();
    for (int i = tid; i < nb; i += 256) atomicAdd(&hist[dl[i]], 1);
    __syncthreads();
    int v = hist[tid];
    sc[tid] = v;
    __syncthreads();
    for (int ofs = 1; ofs < 256; ofs <<= 1) {
        int t = (tid >= ofs) ? sc[tid - ofs] : 0;
        __syncthreads();
        sc[tid] += t;
        __syncthreads();
    }
    int lo = sc[tid] - v;
    if (tid < ndst) off[dbase + tid] = base + lo;
    hist[tid] = lo;
    __syncthreads();
    for (int i = tid; i < nb; i += 256) {
        int r = atomicAdd(&hist[dl[i]], 1);
        csrs[r] = srcs[i];
    }
    __syncthreads();
    for (int i = tid; i < nb; i += 256) csr[base + i] = csrs[i];
}

// ---------------- W1 f32 -> bf16 ----------------

__global__ void k_w1cast(const float* __restrict__ W1, unsigned short* __restrict__ w1b) {
    int i = blockIdx.x * 256 + threadIdx.x;
    if (i < HC * F) w1b[i] = f2bf(W1[i]);
}

// ---------------- gemm1: record.h1 = bf16(x) @ bf16(W1)^T via MFMA ----------------

__global__ __launch_bounds__(256) void k_gemm1(const float* __restrict__ x,
                                               const unsigned short* __restrict__ w1b,
                                               unsigned short* __restrict__ h1r16) {
    __shared__ unsigned short Ws[HC * F];  // 64KB, XOR-swizzled 16B chunks
    for (int i = threadIdx.x; i < 4096; i += 256) {
        int row = i >> 5;
        int c16 = i & 31;
        u32x4 v = ((const u32x4*)w1b)[i];
        int byte = row * 512 + ((c16 * 16) ^ ((row & 7) << 4));
        *((u32x4*)((char*)Ws + byte)) = v;
    }
    __syncthreads();

    int wid = threadIdx.x >> 6, lane = threadIdx.x & 63;
    int r16 = lane & 15, g = lane >> 4;
    int m = blockIdx.x * 64 + wid * 16 + r16;
    int mc = (m < N) ? m : (N - 1);
    const float* xr = x + (size_t)mc * F;

    f32x4 acc[8];
#pragma unroll
    for (int nf = 0; nf < 8; ++nf) acc[nf] = (f32x4){0.f, 0.f, 0.f, 0.f};

#pragma unroll
    for (int kk = 0; kk < 8; ++kk) {
        f32x4 a0 = *((const f32x4*)(xr + kk * 32 + g * 8));
        f32x4 a1 = *((const f32x4*)(xr + kk * 32 + g * 8 + 4));
        short8 af;
#pragma unroll
        for (int j = 0; j < 4; ++j) {
            af[j]     = (short)f2bf(a0[j]);
            af[4 + j] = (short)f2bf(a1[j]);
        }
        int kbyte = kk * 64 + g * 16;
#pragma unroll
        for (int nf = 0; nf < 8; ++nf) {
            int row = nf * 16 + r16;
            int byte = row * 512 + (kbyte ^ ((row & 7) << 4));
            short8 bf = *((const short8*)((const char*)Ws + byte));
            acc[nf] = __builtin_amdgcn_mfma_f32_16x16x32_bf16(af, bf, acc[nf], 0, 0, 0);
        }
    }

    int orow = blockIdx.x * 64 + wid * 16 + g * 4;
#pragma unroll
    for (int j = 0; j < 4; ++j) {
        int rr = orow + j;
        if (rr >= N) continue;
        unsigned short* dst = h1r16 + (size_t)rr * (RECW * 2) + r16;
#pragma unroll
        for (int nf = 0; nf < 8; ++nf) dst[nf * 16] = f2bf(acc[nf][j]);
    }
}

// ---------------- attention scores layer 1 (into record + ad1 array) ----------------

__global__ void k_att1(char* __restrict__ h1r,
                       const float* __restrict__ aw_s, const float* __restrict__ aw_d,
                       float* __restrict__ ad1) {
    int idx = blockIdx.x * 256 + threadIdx.x;  // n*8 + h
    if (idx >= N * H) return;
    int n = idx >> 3, h = idx & 7;
    char* rec = h1r + (size_t)n * (RECW * 4);
    const u32x4* hp = (const u32x4*)(rec + h * 32);
    u32x4 v0 = hp[0], v1 = hp[1];
    float s = 0.f, d = 0.f;
#pragma unroll
    for (int q = 0; q < 4; ++q) {
        unsigned int u = v0[q];
        float e0 = bf2f((unsigned short)(u & 0xffff));
        float e1 = bf2f((unsigned short)(u >> 16));
        s += e0 * aw_s[h * 16 + 2 * q] + e1 * aw_s[h * 16 + 2 * q + 1];
        d += e0 * aw_d[h * 16 + 2 * q] + e1 * aw_d[h * 16 + 2 * q + 1];
    }
#pragma unroll
    for (int q = 0; q < 4; ++q) {
        unsigned int u = v1[q];
        float e0 = bf2f((unsigned short)(u & 0xffff));
        float e1 = bf2f((unsigned short)(u >> 16));
        s += e0 * aw_s[h * 16 + 8 + 2 * q] + e1 * aw_s[h * 16 + 8 + 2 * q + 1];
        d += e0 * aw_d[h * 16 + 8 + 2 * q] + e1 * aw_d[h * 16 + 8 + 2 * q + 1];
    }
    ((float*)(rec + 256))[h] = s;
    ad1[idx] = d;
}

// ---------------- layer 1 aggregate: 16 lanes x 16B per edge, 4 edges/wave-iter ----

__global__ __launch_bounds__(256) void k_agg1(const int* __restrict__ off,
                                              const int* __restrict__ csr,
                                              const unsigned int* __restrict__ h1w,
                                              const float* __restrict__ ad1,
                                              const float* __restrict__ b1,
                                              unsigned short* __restrict__ out1b) {
    int w = threadIdx.x >> 6, l = threadIdx.x & 63;
    int n = blockIdx.x * 4 + w;
    if (n >= N) return;
    int g  = l >> 4;            // edge slot 0..3
    int c8 = l & 15;            // channel block (8 bf16 = 16B)
    int hh = c8 >> 1;           // head of this channel block
    unsigned int wb = (unsigned int)(c8 * 4);   // word offset of channel block
    unsigned int wa = 64u + (unsigned int)hh;   // word offset of as1[hh]
    int e0 = off[n], e1 = off[n + 1];
    int deg = e1 - e0;
    float adst = ad1[n * H + hh];
    float den = 0.f;
    float acc[8] = {0.f, 0.f, 0.f, 0.f, 0.f, 0.f, 0.f, 0.f};

    for (int base = 0; base < deg; base += 64) {
        int nchunk = (deg - base < 64) ? (deg - base) : 64;
        int idx = (l < nchunk) ? csr[e0 + base + l] : 0;
        for (int eb = 0; eb < nchunk; eb += 4) {
            int slot = eb + g;
            bool ok = slot < nchunk;
            int s = __shfl(idx, slot, 64);
            unsigned int r = (unsigned int)s * (unsigned int)RECW;
            float aval = __uint_as_float(h1w[r + wa]);
            float al = aval + adst;
            al = fmaxf(al, al * NEG_SLOPE);          // leaky relu (slope<1)
            float wt = ok ? __expf(al) : 0.f;
            den += wt;
            u32x4 v = *((const u32x4*)(h1w + r + wb));
#pragma unroll
            for (int q = 0; q < 4; ++q) {
                unsigned int u = v[q];
                float lo = __uint_as_float(u << 16);
                float hi = __uint_as_float(u & 0xffff0000u);
                acc[2 * q]     += wt * lo;
                acc[2 * q + 1] += wt * hi;
            }
        }
    }
    // reduce over the 4 edge slots
#pragma unroll
    for (int q = 0; q < 8; ++q) {
        acc[q] += __shfl_xor(acc[q], 16, 64);
        acc[q] += __shfl_xor(acc[q], 32, 64);
    }
    den += __shfl_xor(den, 16, 64);
    den += __shfl_xor(den, 32, 64);

    if (g == 0) {
        float inv = 1.f / (den + 1e-16f);
        unsigned int pk[4];
#pragma unroll
        for (int q = 0; q < 4; ++q) {
            float v0 = acc[2 * q]     * inv + b1[c8 * 8 + 2 * q];
            float v1 = acc[2 * q + 1] * inv + b1[c8 * 8 + 2 * q + 1];
            v0 = (v0 > 0.f) ? v0 : (__expf(v0) - 1.f);   // ELU
            v1 = (v1 > 0.f) ? v1 : (__expf(v1) - 1.f);
            pk[q] = ((unsigned int)f2bf(v1) << 16) | f2bf(v0);
        }
        *((u32x4*)(out1b + (size_t)n * HC + c8 * 8)) = *((u32x4*)pk);
    }
}

// ---------------- layer 2 GEMM (bf16 in) fused with att scores, bf16 h2 out ----

__global__ __launch_bounds__(256) void k_gemm2(const unsigned short* __restrict__ out1b,
                                               const float* __restrict__ W2,
                                               const float* __restrict__ aw_s2,
                                               const float* __restrict__ aw_d2,
                                               unsigned short* __restrict__ h2b,
                                               float* __restrict__ as2,
                                               float* __restrict__ ad2) {
    __shared__ float Ws[HC * NCLS];  // Ws[k*16+j] = W2[j*128+k]
    for (int i = threadIdx.x; i < HC * NCLS; i += 256) {
        int j = i / HC, k = i % HC;
        Ws[k * NCLS + j] = W2[i];
    }
    __syncthreads();
    int gpos = threadIdx.x >> 4, j = threadIdx.x & 15;
    int n = blockIdx.x * 16 + gpos;
    if (n >= N) return;
    const u32x4* xr = (const u32x4*)(out1b + (size_t)n * HC);
    float acc = 0.f;
#pragma unroll
    for (int q = 0; q < 16; ++q) {
        u32x4 v = xr[q];
#pragma unroll
        for (int t = 0; t < 4; ++t) {
            unsigned int u = v[t];
            float e0 = bf2f((unsigned short)(u & 0xffff));
            float e1 = bf2f((unsigned short)(u >> 16));
            acc += e0 * Ws[(q * 8 + 2 * t) * 16 + j] + e1 * Ws[(q * 8 + 2 * t + 1) * 16 + j];
        }
    }
    h2b[n * NCLS + j] = f2bf(acc);
    float s = acc * aw_s2[j], d = acc * aw_d2[j];
#pragma unroll
    for (int msk = 8; msk >= 1; msk >>= 1) {
        s += __shfl_xor(s, msk, 64);
        d += __shfl_xor(d, msk, 64);
    }
    if (j == 0) { as2[n] = s; ad2[n] = d; }
}

// ---------------- layer 2 aggregate (bf16 gather, unrolled x4) + log_softmax ----

__global__ __launch_bounds__(256) void k_agg2(const int* __restrict__ off,
                                              const int* __restrict__ csr,
                                              const float* __restrict__ as2,
                                              const float* __restrict__ ad2,
                                              const unsigned short* __restrict__ h2b,
                                              const float* __restrict__ b2,
                                              float* __restrict__ outp) {
    int gpos = threadIdx.x >> 4, c = threadIdx.x & 15;
    int n = blockIdx.x * 16 + gpos;
    if (n >= N) return;
    int e0 = off[n], e1 = off[n + 1];
    float adst = ad2[n];
    float den = 0.f, acc = 0.f;
    int e = e0;
    for (; e + 4 <= e1; e += 4) {
        int s0 = csr[e], s1 = csr[e + 1], s2 = csr[e + 2], s3 = csr[e + 3];
        float x0 = as2[s0], x1 = as2[s1], x2 = as2[s2], x3 = as2[s3];
        unsigned short m0 = h2b[s0 * NCLS + c], m1 = h2b[s1 * NCLS + c];
        unsigned short m2 = h2b[s2 * NCLS + c], m3 = h2b[s3 * NCLS + c];
        float a0 = x0 + adst; a0 = fmaxf(a0, a0 * NEG_SLOPE);
        float a1 = x1 + adst; a1 = fmaxf(a1, a1 * NEG_SLOPE);
        float a2 = x2 + adst; a2 = fmaxf(a2, a2 * NEG_SLOPE);
        float a3 = x3 + adst; a3 = fmaxf(a3, a3 * NEG_SLOPE);
        float w0 = __expf(a0), w1 = __expf(a1), w2 = __expf(a2), w3 = __expf(a3);
        den += (w0 + w1) + (w2 + w3);
        acc += w0 * bf2f(m0) + w1 * bf2f(m1) + w2 * bf2f(m2) + w3 * bf2f(m3);
    }
    for (; e < e1; ++e) {
        int s = csr[e];
        float al = as2[s] + adst;
        al = fmaxf(al, al * NEG_SLOPE);
        float wt = __expf(al);
        den += wt;
        acc += wt * bf2f(h2b[s * NCLS + c]);
    }
    float v = acc / (den + 1e-16f) + b2[c];
    float mx = v;
#pragma unroll
    for (int msk = 8; msk >= 1; msk >>= 1) mx = fmaxf(mx, __shfl_xor(mx, msk, 64));
    float ex = __expf(v - mx), se = ex;
#pragma unroll
    for (int msk = 8; msk >= 1; msk >>= 1) se += __shfl_xor(se, msk, 64);
    outp[n * NCLS + c] = v - mx - __logf(se);
}

// ---------------- launch ----------------

extern "C" void kernel_launch(void* const* d_in, const int* in_sizes, int n_in,
                              void* d_out, int out_size, void* d_ws, size_t ws_size,
                              hipStream_t stream) {
    const float* x        = (const float*)d_in[0];
    const int*   ei       = (const int*)d_in[1];
    const float* W1       = (const float*)d_in[2];
    const float* att_src1 = (const float*)d_in[3];
    const float* att_dst1 = (const float*)d_in[4];
    const float* b1       = (const float*)d_in[5];
    const float* W2       = (const float*)d_in[6];
    const float* att_src2 = (const float*)d_in[7];
    const float* att_dst2 = (const float*)d_in[8];
    const float* b2       = (const float*)d_in[9];
    float* outp = (float*)d_out;

    char* p = (char*)d_ws;
    char* h1r = p;                             p += (size_t)N * RECW * 4;   // 28.8MB records
    unsigned short* out1b = (unsigned short*)p; p += (size_t)N * HC * 2;    // 25.6MB
    unsigned short* h2b   = (unsigned short*)p; p += (size_t)N * NCLS * 2;  // 3.2MB
    float* ad1  = (float*)p; p += (size_t)N * H * 4;
    float* as2  = (float*)p; p += (size_t)N * 4;
    float* ad2  = (float*)p; p += (size_t)N * 4;
    unsigned short* w1b = (unsigned short*)p; p += (size_t)HC * F * 2;
    uint2* pairs = (uint2*)p; p += (size_t)ETOT * 8;                        // 13.6MB
    int* csr    = (int*)p;   p += (size_t)ETOT * 4;
    int* off    = (int*)p;   p += (size_t)(N + 1) * 4;
    int* bcnt   = (int*)p;   p += (size_t)NBUCK * 4;
    int* boff   = (int*)p;   p += (size_t)NBUCK * 4;
    int* bcur   = (int*)p;   p += (size_t)NBUCK * 4;

    hipMemsetAsync(bcnt, 0, (size_t)NBUCK * 4, stream);

    k_bhist<<<NTILE, 256, 0, stream>>>(ei, bcnt);
    k_bscan<<<1, 512, 0, stream>>>(bcnt, boff, bcur, off);
    k_part<<<NTILE, 256, 0, stream>>>(ei, bcur, pairs);
    k_bsort<<<NBUCK, 256, 0, stream>>>(pairs, bcnt, boff, csr, off);

    k_w1cast<<<(HC * F + 255) / 256, 256, 0, stream>>>(W1, w1b);
    k_gemm1<<<(N + 63) / 64, 256, 0, stream>>>(x, w1b, (unsigned short*)h1r);
    k_att1<<<(N * H + 255) / 256, 256, 0, stream>>>(h1r, att_src1, att_dst1, ad1);
    k_agg1<<<(N + 3) / 4, 256, 0, stream>>>(off, csr, (const unsigned int*)h1r, ad1, b1, out1b);

    k_gemm2<<<(N + 15) / 16, 256, 0, stream>>>(out1b, W2, att_src2, att_dst2, h2b, as2, ad2);
    k_agg2<<<(N + 15) / 16, 256, 0, stream>>>(off, csr, as2, ad2, h2b, b2, outp);
}